// Round 1
// baseline (612.126 us; speedup 1.0000x reference)
//
#include <hip/hip_runtime.h>
#include <math.h>

// Shapes (fixed by the reference)
constexpr int Bn  = 16;
constexpr int Sn  = 512;
constexpr int S2n = 64;
constexpr int Hn  = 128;
constexpr int Ln  = 3;

#define TID ((int)threadIdx.x)

__device__ inline float wave_reduce_sum(float v) {
#pragma unroll
  for (int off = 32; off > 0; off >>= 1) v += __shfl_xor(v, off, 64);
  return v;
}

// All threads return the block-wide sum. Includes trailing barrier so `red`
// can be reused by consecutive calls.
__device__ inline float block_reduce_sum(float v, float* red) {
  v = wave_reduce_sum(v);
  int w  = TID >> 6;
  int nw = (int)blockDim.x >> 6;
  if ((TID & 63) == 0) red[w] = v;
  __syncthreads();
  float s = 0.f;
  for (int i = 0; i < nw; ++i) s += red[i];
  __syncthreads();
  return s;
}

// Y[M,128] = X[M,K] @ W[:, woff:woff+K]^T (+bias if !accum) (+= if accum)
// W rows are at W[n*wstride + woff + k], n in [0,128). 256 threads,
// 16 rows per block; X tile staged in LDS, W read per-thread (L2-served).
__global__ __launch_bounds__(256) void gemm_xwT(
    const float* __restrict__ X, const float* __restrict__ W,
    const float* __restrict__ bias, float* __restrict__ Y,
    int M, int K, int wstride, int woff, int accum)
{
  __shared__ float Xs[16 * 256];
  int r0 = blockIdx.x * 16;
  const float* xsrc = X + (size_t)r0 * K;
  int tot4 = (16 * K) >> 2;
  for (int i = TID; i < tot4; i += 256)
    ((float4*)Xs)[i] = ((const float4*)xsrc)[i];
  __syncthreads();

  int col   = TID & 127;
  int rbase = (TID >> 7) * 8;
  const float* wrow = W + (size_t)col * wstride + woff;
  float acc[8] = {0.f,0.f,0.f,0.f,0.f,0.f,0.f,0.f};

#pragma unroll 2
  for (int k = 0; k < K; k += 4) {
    float4 w = *(const float4*)(wrow + k);
#pragma unroll
    for (int r = 0; r < 8; ++r) {
      float4 x = *(const float4*)&Xs[(rbase + r) * K + k];
      acc[r] = fmaf(w.x, x.x, acc[r]);
      acc[r] = fmaf(w.y, x.y, acc[r]);
      acc[r] = fmaf(w.z, x.z, acc[r]);
      acc[r] = fmaf(w.w, x.w, acc[r]);
    }
  }
  float bv = bias ? bias[col] : 0.f;
#pragma unroll
  for (int r = 0; r < 8; ++r) {
    float* y = Y + (size_t)(r0 + rbase + r) * 128 + col;
    if (accum) *y += acc[r];
    else       *y  = acc[r] + bv;
  }
}

// a[b,i,c] = sum_j adj[b,i,j] * x[b,j,c]; x = cat(p,h) along channel.
// 16 adjacency rows staged in LDS per block; 256 threads = channel index.
__global__ __launch_bounds__(256) void adj_mm(
    const float* __restrict__ adj, const float* __restrict__ p,
    const float* __restrict__ h, float* __restrict__ a)
{
  __shared__ float As[16 * 512];
  int b = blockIdx.y, i0 = blockIdx.x * 16;
  const float* src = adj + ((size_t)b * Sn + i0) * Sn;
  for (int i = TID; i < (16 * 512) >> 2; i += 256)
    ((float4*)As)[i] = ((const float4*)src)[i];
  __syncthreads();

  int c = TID;
  const float* xcol = (c < Hn) ? (p + (size_t)b * Sn * Hn + c)
                               : (h + (size_t)b * Sn * Hn + (c - Hn));
  float acc[16];
#pragma unroll
  for (int r = 0; r < 16; ++r) acc[r] = 0.f;

  for (int j = 0; j < Sn; j += 4) {
    float x0 = xcol[(size_t)(j + 0) * Hn];
    float x1 = xcol[(size_t)(j + 1) * Hn];
    float x2 = xcol[(size_t)(j + 2) * Hn];
    float x3 = xcol[(size_t)(j + 3) * Hn];
#pragma unroll
    for (int r = 0; r < 16; ++r) {
      float4 av = *(const float4*)&As[r * 512 + j];
      acc[r] = fmaf(av.x, x0, acc[r]);
      acc[r] = fmaf(av.y, x1, acc[r]);
      acc[r] = fmaf(av.z, x2, acc[r]);
      acc[r] = fmaf(av.w, x3, acc[r]);
    }
  }
  float* dst = a + ((size_t)b * Sn + i0) * (2 * Hn) + c;
#pragma unroll
  for (int r = 0; r < 16; ++r) dst[(size_t)r * (2 * Hn)] = acc[r];
}

// rp <- sigmoid(rp) * h   (elementwise, float4)
__global__ void rh_fuse(const float* __restrict__ h, float* __restrict__ rp, int n4) {
  int i = blockIdx.x * blockDim.x + TID;
  if (i >= n4) return;
  float4 r  = ((const float4*)rp)[i];
  float4 hv = ((const float4*)h)[i];
  r.x = hv.x / (1.f + expf(-r.x));
  r.y = hv.y / (1.f + expf(-r.y));
  r.z = hv.z / (1.f + expf(-r.z));
  r.w = hv.w / (1.f + expf(-r.w));
  ((float4*)rp)[i] = r;
}

// h <- (1-sigmoid(zp))*h + sigmoid(zp)*tanh(hp)
__global__ void gate_combine(float* __restrict__ h, const float* __restrict__ zp,
                             const float* __restrict__ hp, int n4) {
  int i = blockIdx.x * blockDim.x + TID;
  if (i >= n4) return;
  float4 hv = ((const float4*)h)[i];
  float4 z4 = ((const float4*)zp)[i];
  float4 t4 = ((const float4*)hp)[i];
  float z;
  z = 1.f / (1.f + expf(-z4.x)); hv.x = hv.x + z * (tanhf(t4.x) - hv.x);
  z = 1.f / (1.f + expf(-z4.y)); hv.y = hv.y + z * (tanhf(t4.y) - hv.y);
  z = 1.f / (1.f + expf(-z4.z)); hv.z = hv.z + z * (tanhf(t4.z) - hv.z);
  z = 1.f / (1.f + expf(-z4.w)); hv.w = hv.w + z * (tanhf(t4.w) - hv.w);
  ((float4*)h)[i] = hv;
}

// E[b,q,k] = mask ? exp(relu(Wa2 . relu(qp[b,q]+kp[b,k]+ba1) + ba2)) : 0
// One wave per (q,k) pair: lane l covers channels 2l, 2l+1.
__global__ __launch_bounds__(256) void scores_exp(
    const float* __restrict__ qp, const float* __restrict__ kp,
    const float* __restrict__ ba1, const float* __restrict__ Wa2,
    const float* __restrict__ ba2, const float* __restrict__ am,
    const float* __restrict__ sm, float* __restrict__ E)
{
  int b = blockIdx.y, q = blockIdx.x;
  int w = TID >> 6, l = TID & 63;
  float2 qv = *(const float2*)(qp + ((size_t)b * S2n + q) * Hn + 2 * l);
  float2 b1 = *(const float2*)(ba1 + 2 * l);
  float2 w2 = *(const float2*)(Wa2 + 2 * l);
  float q0 = qv.x + b1.x, q1 = qv.y + b1.y;
  float amq = am[b * S2n + q];
  float b2  = ba2[0];
  float* Erow = E + ((size_t)b * S2n + q) * Sn;
  const float* kbase = kp + (size_t)b * Sn * Hn + 2 * l;

  for (int k = w; k < Sn; k += 4) {
    float2 kv = *(const float2*)(kbase + (size_t)k * Hn);
    float v = fmaxf(q0 + kv.x, 0.f) * w2.x + fmaxf(q1 + kv.y, 0.f) * w2.y;
    v = wave_reduce_sum(v);
    if (l == 0) {
      float s = fmaxf(v + b2, 0.f);
      float m = amq * sm[b * Sn + k];
      Erow[k] = (m > 0.f) ? expf(s) : 0.f;
    }
  }
}

// sf[b,q,:] = (1/max(sum_k E,2e-15)) * sum_k E[b,q,k]*out[b,k,:]
__global__ __launch_bounds__(128) void attn_sf(
    const float* __restrict__ E, const float* __restrict__ out,
    float* __restrict__ sf)
{
  __shared__ float Es[512];
  __shared__ float red[2];
  int b = blockIdx.y, q = blockIdx.x, t = TID;
  const float* Erow = E + ((size_t)b * S2n + q) * Sn;
  for (int i = t; i < Sn; i += 128) Es[i] = Erow[i];
  __syncthreads();
  float part = Es[t] + Es[t + 128] + Es[t + 256] + Es[t + 384];
  part = wave_reduce_sum(part);
  if ((t & 63) == 0) red[t >> 6] = part;
  __syncthreads();
  float scale = 1.f / fmaxf(red[0] + red[1], 2e-15f);

  const float* ob = out + (size_t)b * Sn * Hn + t;
  float acc = 0.f;
#pragma unroll 8
  for (int k = 0; k < Sn; ++k) acc = fmaf(Es[k], ob[(size_t)k * Hn], acc);
  sf[((size_t)b * S2n + q) * Hn + t] = acc * scale;
}

// sem[b,:] = sum_q sf[b,q,:] / sum_q actions_mask[b,q]
__global__ __launch_bounds__(128) void sem_mean(
    const float* __restrict__ sf, const float* __restrict__ am,
    float* __restrict__ sem)
{
  int b = blockIdx.x, t = TID;
  float acc = 0.f;
  for (int q = 0; q < S2n; ++q) acc += sf[((size_t)b * S2n + q) * Hn + t];
  float num = 0.f;
  for (int i = 0; i < S2n; ++i) num += am[b * S2n + i];
  sem[b * Hn + t] = acc / num;
}

// adv[b,s,l] = sum_h actions[b,s,h] * (weight[l] @ sf[b,s])_h + bias[l]
__global__ __launch_bounds__(128) void adv_kernel(
    const float* __restrict__ actions, const float* __restrict__ sf,
    const float* __restrict__ weight, const float* __restrict__ bias,
    float* __restrict__ adv)
{
  __shared__ float acts[128], sfs[128];
  __shared__ float red[2];
  int b = blockIdx.y, s = blockIdx.x, t = TID;
  size_t row = (size_t)b * S2n + s;
  acts[t] = actions[row * Hn + t];
  sfs[t]  = sf[row * Hn + t];
  __syncthreads();
  for (int l = 0; l < Ln; ++l) {
    const float* wr = weight + ((size_t)l * Hn + t) * Hn;
    float tmp = 0.f;
#pragma unroll 4
    for (int k = 0; k < Hn; k += 4) {
      float4 wv = *(const float4*)(wr + k);
      tmp = fmaf(wv.x, sfs[k],     tmp);
      tmp = fmaf(wv.y, sfs[k + 1], tmp);
      tmp = fmaf(wv.z, sfs[k + 2], tmp);
      tmp = fmaf(wv.w, sfs[k + 3], tmp);
    }
    float pa  = acts[t] * tmp;
    float tot = block_reduce_sum(pa, red);
    if (t == 0) adv[row * Ln + l] = tot + bias[l];
  }
}

// q[b,s,l] = val_b + adv[b,s,l] - mean_{s,l}(adv[b]) ; val_b = Wv.sem[b]+bv
__global__ __launch_bounds__(256) void final_kernel(
    const float* __restrict__ sem, const float* __restrict__ Wv,
    const float* __restrict__ bv, const float* __restrict__ adv,
    float* __restrict__ outq)
{
  __shared__ float red[4];
  int b = blockIdx.x, t = TID;
  float pv  = (t < Hn) ? Wv[t] * sem[b * Hn + t] : 0.f;
  float val = block_reduce_sum(pv, red) + bv[0];
  const float* advb = adv + (size_t)b * S2n * Ln;
  float pa   = (t < S2n * Ln) ? advb[t] : 0.f;
  float mean = block_reduce_sum(pa, red) / (float)(S2n * Ln);
  for (int i = t; i < S2n * Ln; i += 256)
    outq[(size_t)b * S2n * Ln + i] = val + advb[i] - mean;
}

extern "C" void kernel_launch(void* const* d_in, const int* in_sizes, int n_in,
                              void* d_out, int out_size, void* d_ws, size_t ws_size,
                              hipStream_t stream)
{
  const float* states       = (const float*)d_in[0];
  const float* state_mask   = (const float*)d_in[1];
  const float* actions      = (const float*)d_in[2];
  const float* actions_mask = (const float*)d_in[3];
  const float* adj          = (const float*)d_in[4];
  const float* Wn  = (const float*)d_in[5];
  const float* bn  = (const float*)d_in[6];
  const float* Wu  = (const float*)d_in[7];
  const float* bu  = (const float*)d_in[8];
  const float* Wr  = (const float*)d_in[9];
  const float* br  = (const float*)d_in[10];
  const float* Wt  = (const float*)d_in[11];
  const float* bt  = (const float*)d_in[12];
  const float* Wa1 = (const float*)d_in[13];
  const float* ba1 = (const float*)d_in[14];
  const float* Wa2 = (const float*)d_in[15];
  const float* ba2 = (const float*)d_in[16];
  const float* Wv  = (const float*)d_in[17];
  const float* bvp = (const float*)d_in[18];
  const float* weight = (const float*)d_in[19];
  const float* bias   = (const float*)d_in[20];

  // Workspace layout (floats). Total 6 * 2^20 floats = 24 MB.
  float* ws  = (float*)d_ws;
  float* h   = ws;                 // [B,S,H]   1,048,576
  float* p   = ws + (1 << 20);     // [B,S,H]
  float* a   = ws + 2 * (1 << 20); // [B,S,2H]  2,097,152
  float* zp  = ws + 4 * (1 << 20); // [B,S,H]
  float* rp  = ws + 5 * (1 << 20); // [B,S,H]
  float* hp  = a;                  // reuse (a dead after zp/rp gemms)
  float* qp  = a + (1 << 20);      // reuse after GGNN loop (131,072)
  float* kp  = p;                  // reuse after GGNN loop
  float* E   = zp;                 // [B,S2,S] 524,288 (reuse after loop)
  float* sfb = rp;                 // [B,S2,H] 131,072 (reuse after loop)
  float* sem = rp + 135168;        // [B,H]    2,048
  float* adv = rp + 139264;        // [B,S2,L] 3,072

  const int M  = Bn * Sn;          // 8192
  const int n4 = (M * Hn) / 4;     // 262,144

  hipMemcpyAsync(h, states, sizeof(float) * (size_t)M * Hn,
                 hipMemcpyDeviceToDevice, stream);

  for (int step = 0; step < 3; ++step) {
    // p = h @ Wn^T + bn
    gemm_xwT<<<M / 16, 256, 0, stream>>>(h, Wn, bn, p, M, 128, 128, 0, 0);
    // a = adj @ cat(p, h)
    adj_mm<<<dim3(Sn / 16, Bn), 256, 0, stream>>>(adj, p, h, a);
    // zp = a @ Wu^T + bu ; rp = a @ Wr^T + br
    gemm_xwT<<<M / 16, 256, 0, stream>>>(a, Wu, bu, zp, M, 256, 256, 0, 0);
    gemm_xwT<<<M / 16, 256, 0, stream>>>(a, Wr, br, rp, M, 256, 256, 0, 0);
    // rp <- sigmoid(rp) * h
    rh_fuse<<<n4 / 256, 256, 0, stream>>>(h, rp, n4);
    // hp = p @ WtL^T + bt ; hp += (r*h) @ WtR^T
    gemm_xwT<<<M / 16, 256, 0, stream>>>(p, Wt, bt, hp, M, 128, 256, 0, 0);
    gemm_xwT<<<M / 16, 256, 0, stream>>>(rp, Wt, nullptr, hp, M, 128, 256, 128, 1);
    // h <- (1-z)*h + z*tanh(hp)
    gate_combine<<<n4 / 256, 256, 0, stream>>>(h, zp, hp, n4);
  }

  // qp = actions @ Wa1[:, :H]^T ; kp = out @ Wa1[:, H:]^T   (no bias here)
  gemm_xwT<<<(Bn * S2n) / 16, 256, 0, stream>>>(actions, Wa1, nullptr, qp,
                                                Bn * S2n, 128, 256, 0, 0);
  gemm_xwT<<<M / 16, 256, 0, stream>>>(h, Wa1, nullptr, kp, M, 128, 256, 128, 0);

  scores_exp<<<dim3(S2n, Bn), 256, 0, stream>>>(qp, kp, ba1, Wa2, ba2,
                                                actions_mask, state_mask, E);
  attn_sf<<<dim3(S2n, Bn), 128, 0, stream>>>(E, h, sfb);
  sem_mean<<<Bn, 128, 0, stream>>>(sfb, actions_mask, sem);
  adv_kernel<<<dim3(S2n, Bn), 128, 0, stream>>>(actions, sfb, weight, bias, adv);
  final_kernel<<<Bn, 256, 0, stream>>>(sem, Wv, bvp, adv, (float*)d_out);
}

// Round 3
// 536.591 us; speedup vs baseline: 1.1408x; 1.1408x over previous
//
#include <hip/hip_runtime.h>
#include <math.h>

// Shapes (fixed by the reference)
constexpr int Bn  = 16;
constexpr int Sn  = 512;
constexpr int S2n = 64;
constexpr int Hn  = 128;
constexpr int Ln  = 3;

#define TID ((int)threadIdx.x)

__device__ inline float wave_reduce_sum(float v) {
#pragma unroll
  for (int off = 32; off > 0; off >>= 1) v += __shfl_xor(v, off, 64);
  return v;
}

// All threads return the block-wide sum. Includes trailing barrier so `red`
// can be reused by consecutive calls.
__device__ inline float block_reduce_sum(float v, float* red) {
  v = wave_reduce_sum(v);
  int w  = TID >> 6;
  int nw = (int)blockDim.x >> 6;
  if ((TID & 63) == 0) red[w] = v;
  __syncthreads();
  float s = 0.f;
  for (int i = 0; i < nw; ++i) s += red[i];
  __syncthreads();
  return s;
}

// Y[M,128] = X[M,K] @ W[:, woff:woff+K]^T (+bias if !accum) (+= if accum)
// W rows are at W[n*wstride + woff + k], n in [0,128). 256 threads,
// 16 rows per block; X tile staged in LDS, W read per-thread (L2-served).
__global__ __launch_bounds__(256) void gemm_xwT(
    const float* __restrict__ X, const float* __restrict__ W,
    const float* __restrict__ bias, float* __restrict__ Y,
    int M, int K, int wstride, int woff, int accum)
{
  __shared__ float Xs[16 * 256];
  int r0 = blockIdx.x * 16;
  const float* xsrc = X + (size_t)r0 * K;
  int tot4 = (16 * K) >> 2;
  for (int i = TID; i < tot4; i += 256)
    ((float4*)Xs)[i] = ((const float4*)xsrc)[i];
  __syncthreads();

  int col   = TID & 127;
  int rbase = (TID >> 7) * 8;
  const float* wrow = W + (size_t)col * wstride + woff;
  float acc[8] = {0.f,0.f,0.f,0.f,0.f,0.f,0.f,0.f};

#pragma unroll 2
  for (int k = 0; k < K; k += 4) {
    float4 w = *(const float4*)(wrow + k);
#pragma unroll
    for (int r = 0; r < 8; ++r) {
      float4 x = *(const float4*)&Xs[(rbase + r) * K + k];
      acc[r] = fmaf(w.x, x.x, acc[r]);
      acc[r] = fmaf(w.y, x.y, acc[r]);
      acc[r] = fmaf(w.z, x.z, acc[r]);
      acc[r] = fmaf(w.w, x.w, acc[r]);
    }
  }
  float bv = bias ? bias[col] : 0.f;
#pragma unroll
  for (int r = 0; r < 8; ++r) {
    float* y = Y + (size_t)(r0 + rbase + r) * 128 + col;
    if (accum) *y += acc[r];
    else       *y  = acc[r] + bv;
  }
}

// a[b,i,c] = sum_j adj[b,i,j] * x[b,j,c]; x = cat(p,h) along channel.
// 16 adjacency rows staged in LDS per block; 256 threads = channel index.
__global__ __launch_bounds__(256) void adj_mm(
    const float* __restrict__ adj, const float* __restrict__ p,
    const float* __restrict__ h, float* __restrict__ a)
{
  __shared__ float As[16 * 512];
  int b = blockIdx.y, i0 = blockIdx.x * 16;
  const float* src = adj + ((size_t)b * Sn + i0) * Sn;
  for (int i = TID; i < (16 * 512) >> 2; i += 256)
    ((float4*)As)[i] = ((const float4*)src)[i];
  __syncthreads();

  int c = TID;
  const float* xcol = (c < Hn) ? (p + (size_t)b * Sn * Hn + c)
                               : (h + (size_t)b * Sn * Hn + (c - Hn));
  float acc[16];
#pragma unroll
  for (int r = 0; r < 16; ++r) acc[r] = 0.f;

  for (int j = 0; j < Sn; j += 4) {
    float x0 = xcol[(size_t)(j + 0) * Hn];
    float x1 = xcol[(size_t)(j + 1) * Hn];
    float x2 = xcol[(size_t)(j + 2) * Hn];
    float x3 = xcol[(size_t)(j + 3) * Hn];
#pragma unroll
    for (int r = 0; r < 16; ++r) {
      float4 av = *(const float4*)&As[r * 512 + j];
      acc[r] = fmaf(av.x, x0, acc[r]);
      acc[r] = fmaf(av.y, x1, acc[r]);
      acc[r] = fmaf(av.z, x2, acc[r]);
      acc[r] = fmaf(av.w, x3, acc[r]);
    }
  }
  float* dst = a + ((size_t)b * Sn + i0) * (2 * Hn) + c;
#pragma unroll
  for (int r = 0; r < 16; ++r) dst[(size_t)r * (2 * Hn)] = acc[r];
}

// rp <- sigmoid(rp) * h   (elementwise, float4)
__global__ void rh_fuse(const float* __restrict__ h, float* __restrict__ rp, int n4) {
  int i = blockIdx.x * blockDim.x + TID;
  if (i >= n4) return;
  float4 r  = ((const float4*)rp)[i];
  float4 hv = ((const float4*)h)[i];
  r.x = hv.x / (1.f + expf(-r.x));
  r.y = hv.y / (1.f + expf(-r.y));
  r.z = hv.z / (1.f + expf(-r.z));
  r.w = hv.w / (1.f + expf(-r.w));
  ((float4*)rp)[i] = r;
}

// h <- (1-sigmoid(zp))*h + sigmoid(zp)*tanh(hp)
__global__ void gate_combine(float* __restrict__ h, const float* __restrict__ zp,
                             const float* __restrict__ hp, int n4) {
  int i = blockIdx.x * blockDim.x + TID;
  if (i >= n4) return;
  float4 hv = ((const float4*)h)[i];
  float4 z4 = ((const float4*)zp)[i];
  float4 t4 = ((const float4*)hp)[i];
  float z;
  z = 1.f / (1.f + expf(-z4.x)); hv.x = hv.x + z * (tanhf(t4.x) - hv.x);
  z = 1.f / (1.f + expf(-z4.y)); hv.y = hv.y + z * (tanhf(t4.y) - hv.y);
  z = 1.f / (1.f + expf(-z4.z)); hv.z = hv.z + z * (tanhf(t4.z) - hv.z);
  z = 1.f / (1.f + expf(-z4.w)); hv.w = hv.w + z * (tanhf(t4.w) - hv.w);
  ((float4*)h)[i] = hv;
}

// E[b,q,k] = mask ? exp(relu(Wa2 . relu(qp[b,q]+kp[b,k]+ba1) + ba2)) : 0
// v2: block = (b, k-tile of 32) covering all 64 q. LDS-staged padded tiles,
// each thread register-blocks 4q x 2k, full h-dot per thread (no cross-lane
// reduce). E bounced through LDS for coalesced stores.
__global__ __launch_bounds__(256) void scores_exp_v2(
    const float* __restrict__ qp, const float* __restrict__ kp,
    const float* __restrict__ ba1, const float* __restrict__ Wa2,
    const float* __restrict__ ba2, const float* __restrict__ am,
    const float* __restrict__ sm, float* __restrict__ E)
{
  constexpr int KT = 32;
  __shared__ float qs[64][132];   // qp + ba1, padded (132*4B % 16 == 0)
  __shared__ float ks[KT][132];
  __shared__ float w2s[128];
  __shared__ float es[64][33];

  int b = blockIdx.y, kt = blockIdx.x * KT;

  const float* qsrc = qp + (size_t)b * S2n * Hn;
  for (int f = TID; f < 64 * 32; f += 256) {     // float4 index
    int q = f >> 5, g = f & 31;
    float4 v  = ((const float4*)qsrc)[f];
    float4 bb = ((const float4*)ba1)[g];
    v.x += bb.x; v.y += bb.y; v.z += bb.z; v.w += bb.w;
    *(float4*)&qs[q][4 * g] = v;
  }
  const float* ksrc = kp + ((size_t)b * Sn + kt) * Hn;
  for (int f = TID; f < KT * 32; f += 256) {
    int k = f >> 5, g = f & 31;
    *(float4*)&ks[k][4 * g] = ((const float4*)ksrc)[f];
  }
  if (TID < 128) w2s[TID] = Wa2[TID];
  __syncthreads();

  const int q0 = (TID & 15) * 4;       // 16 groups x 4 q = 64 q
  const int k0 = (TID >> 4) * 2;       // 16 groups x 2 k = 32 k
  float acc[4][2] = {};

#pragma unroll 4
  for (int h = 0; h < 128; ++h) {
    float w  = w2s[h];
    float kv0 = ks[k0][h], kv1 = ks[k0 + 1][h];
#pragma unroll
    for (int i = 0; i < 4; ++i) {
      float qv = qs[q0 + i][h];
      acc[i][0] = fmaf(fmaxf(qv + kv0, 0.f), w, acc[i][0]);
      acc[i][1] = fmaf(fmaxf(qv + kv1, 0.f), w, acc[i][1]);
    }
  }

  float b2 = ba2[0];
#pragma unroll
  for (int i = 0; i < 4; ++i) {
    float amq = am[b * S2n + q0 + i];
#pragma unroll
    for (int j = 0; j < 2; ++j) {
      float m = amq * sm[b * Sn + kt + k0 + j];
      float s = fmaxf(acc[i][j] + b2, 0.f);
      es[q0 + i][k0 + j] = (m > 0.f) ? expf(s) : 0.f;
    }
  }
  __syncthreads();

  float* Eb = E + ((size_t)b * S2n) * Sn + kt;
  for (int f = TID; f < 64 * KT; f += 256) {
    int q = f >> 5, kin = f & 31;
    Eb[(size_t)q * Sn + kin] = es[q][kin];
  }
}

// sf[b,q,:] = (1/max(sum_k E,2e-15)) * sum_k E[b,q,k]*out[b,k,:]
__global__ __launch_bounds__(128) void attn_sf(
    const float* __restrict__ E, const float* __restrict__ out,
    float* __restrict__ sf)
{
  __shared__ float Es[512];
  __shared__ float red[2];
  int b = blockIdx.y, q = blockIdx.x, t = TID;
  const float* Erow = E + ((size_t)b * S2n + q) * Sn;
  for (int i = t; i < Sn; i += 128) Es[i] = Erow[i];
  __syncthreads();
  float part = Es[t] + Es[t + 128] + Es[t + 256] + Es[t + 384];
  part = wave_reduce_sum(part);
  if ((t & 63) == 0) red[t >> 6] = part;
  __syncthreads();
  float scale = 1.f / fmaxf(red[0] + red[1], 2e-15f);

  const float* ob = out + (size_t)b * Sn * Hn + t;
  float acc = 0.f;
#pragma unroll 8
  for (int k = 0; k < Sn; ++k) acc = fmaf(Es[k], ob[(size_t)k * Hn], acc);
  sf[((size_t)b * S2n + q) * Hn + t] = acc * scale;
}

// sem[b,:] = sum_q sf[b,q,:] / sum_q actions_mask[b,q]
__global__ __launch_bounds__(128) void sem_mean(
    const float* __restrict__ sf, const float* __restrict__ am,
    float* __restrict__ sem)
{
  int b = blockIdx.x, t = TID;
  float acc = 0.f;
  for (int q = 0; q < S2n; ++q) acc += sf[((size_t)b * S2n + q) * Hn + t];
  float num = 0.f;
  for (int i = 0; i < S2n; ++i) num += am[b * S2n + i];
  sem[b * Hn + t] = acc / num;
}

// adv[b,s,l] = sum_h actions[b,s,h] * (weight[l] @ sf[b,s])_h + bias[l]
__global__ __launch_bounds__(128) void adv_kernel(
    const float* __restrict__ actions, const float* __restrict__ sf,
    const float* __restrict__ weight, const float* __restrict__ bias,
    float* __restrict__ adv)
{
  __shared__ float acts[128], sfs[128];
  __shared__ float red[2];
  int b = blockIdx.y, s = blockIdx.x, t = TID;
  size_t row = (size_t)b * S2n + s;
  acts[t] = actions[row * Hn + t];
  sfs[t]  = sf[row * Hn + t];
  __syncthreads();
  for (int l = 0; l < Ln; ++l) {
    const float* wr = weight + ((size_t)l * Hn + t) * Hn;
    float tmp = 0.f;
#pragma unroll 4
    for (int k = 0; k < Hn; k += 4) {
      float4 wv = *(const float4*)(wr + k);
      tmp = fmaf(wv.x, sfs[k],     tmp);
      tmp = fmaf(wv.y, sfs[k + 1], tmp);
      tmp = fmaf(wv.z, sfs[k + 2], tmp);
      tmp = fmaf(wv.w, sfs[k + 3], tmp);
    }
    float pa  = acts[t] * tmp;
    float tot = block_reduce_sum(pa, red);
    if (t == 0) adv[row * Ln + l] = tot + bias[l];
  }
}

// q[b,s,l] = val_b + adv[b,s,l] - mean_{s,l}(adv[b]) ; val_b = Wv.sem[b]+bv
__global__ __launch_bounds__(256) void final_kernel(
    const float* __restrict__ sem, const float* __restrict__ Wv,
    const float* __restrict__ bv, const float* __restrict__ adv,
    float* __restrict__ outq)
{
  __shared__ float red[4];
  int b = blockIdx.x, t = TID;
  float pv  = (t < Hn) ? Wv[t] * sem[b * Hn + t] : 0.f;
  float val = block_reduce_sum(pv, red) + bv[0];
  const float* advb = adv + (size_t)b * S2n * Ln;
  float pa   = (t < S2n * Ln) ? advb[t] : 0.f;
  float mean = block_reduce_sum(pa, red) / (float)(S2n * Ln);
  for (int i = t; i < S2n * Ln; i += 256)
    outq[(size_t)b * S2n * Ln + i] = val + advb[i] - mean;
}

extern "C" void kernel_launch(void* const* d_in, const int* in_sizes, int n_in,
                              void* d_out, int out_size, void* d_ws, size_t ws_size,
                              hipStream_t stream)
{
  const float* states       = (const float*)d_in[0];
  const float* state_mask   = (const float*)d_in[1];
  const float* actions      = (const float*)d_in[2];
  const float* actions_mask = (const float*)d_in[3];
  const float* adj          = (const float*)d_in[4];
  const float* Wn  = (const float*)d_in[5];
  const float* bn  = (const float*)d_in[6];
  const float* Wu  = (const float*)d_in[7];
  const float* bu  = (const float*)d_in[8];
  const float* Wr  = (const float*)d_in[9];
  const float* br  = (const float*)d_in[10];
  const float* Wt  = (const float*)d_in[11];
  const float* bt  = (const float*)d_in[12];
  const float* Wa1 = (const float*)d_in[13];
  const float* ba1 = (const float*)d_in[14];
  const float* Wa2 = (const float*)d_in[15];
  const float* ba2 = (const float*)d_in[16];
  const float* Wv  = (const float*)d_in[17];
  const float* bvp = (const float*)d_in[18];
  const float* weight = (const float*)d_in[19];
  const float* bias   = (const float*)d_in[20];

  // Workspace layout (floats). Total 6 * 2^20 floats = 24 MB.
  float* ws  = (float*)d_ws;
  float* h   = ws;                 // [B,S,H]   1,048,576
  float* p   = ws + (1 << 20);     // [B,S,H]
  float* a   = ws + 2 * (1 << 20); // [B,S,2H]  2,097,152
  float* zp  = ws + 4 * (1 << 20); // [B,S,H]
  float* rp  = ws + 5 * (1 << 20); // [B,S,H]
  float* hp  = a;                  // reuse (a dead after zp/rp gemms)
  float* qp  = a + (1 << 20);      // reuse after GGNN loop (131,072)
  float* kp  = p;                  // reuse after GGNN loop
  float* E   = zp;                 // [B,S2,S] 524,288 (reuse after loop)
  float* sfb = rp;                 // [B,S2,H] 131,072 (reuse after loop)
  float* sem = rp + 135168;        // [B,H]    2,048
  float* adv = rp + 139264;        // [B,S2,L] 3,072

  const int M  = Bn * Sn;          // 8192
  const int n4 = (M * Hn) / 4;     // 262,144

  hipMemcpyAsync(h, states, sizeof(float) * (size_t)M * Hn,
                 hipMemcpyDeviceToDevice, stream);

  for (int step = 0; step < 3; ++step) {
    // p = h @ Wn^T + bn
    gemm_xwT<<<M / 16, 256, 0, stream>>>(h, Wn, bn, p, M, 128, 128, 0, 0);
    // a = adj @ cat(p, h)
    adj_mm<<<dim3(Sn / 16, Bn), 256, 0, stream>>>(adj, p, h, a);
    // zp = a @ Wu^T + bu ; rp = a @ Wr^T + br
    gemm_xwT<<<M / 16, 256, 0, stream>>>(a, Wu, bu, zp, M, 256, 256, 0, 0);
    gemm_xwT<<<M / 16, 256, 0, stream>>>(a, Wr, br, rp, M, 256, 256, 0, 0);
    // rp <- sigmoid(rp) * h
    rh_fuse<<<n4 / 256, 256, 0, stream>>>(h, rp, n4);
    // hp = p @ WtL^T + bt ; hp += (r*h) @ WtR^T
    gemm_xwT<<<M / 16, 256, 0, stream>>>(p, Wt, bt, hp, M, 128, 256, 0, 0);
    gemm_xwT<<<M / 16, 256, 0, stream>>>(rp, Wt, nullptr, hp, M, 128, 256, 128, 1);
    // h <- (1-z)*h + z*tanh(hp)
    gate_combine<<<n4 / 256, 256, 0, stream>>>(h, zp, hp, n4);
  }

  // qp = actions @ Wa1[:, :H]^T ; kp = out @ Wa1[:, H:]^T   (no bias here)
  gemm_xwT<<<(Bn * S2n) / 16, 256, 0, stream>>>(actions, Wa1, nullptr, qp,
                                                Bn * S2n, 128, 256, 0, 0);
  gemm_xwT<<<M / 16, 256, 0, stream>>>(h, Wa1, nullptr, kp, M, 128, 256, 128, 0);

  scores_exp_v2<<<dim3(Sn / 32, Bn), 256, 0, stream>>>(qp, kp, ba1, Wa2, ba2,
                                                       actions_mask, state_mask, E);
  attn_sf<<<dim3(S2n, Bn), 128, 0, stream>>>(E, h, sfb);
  sem_mean<<<Bn, 128, 0, stream>>>(sfb, actions_mask, sem);
  adv_kernel<<<dim3(S2n, Bn), 128, 0, stream>>>(actions, sfb, weight, bias, adv);
  final_kernel<<<Bn, 256, 0, stream>>>(sem, Wv, bvp, adv, (float*)d_out);
}

// Round 6
// 532.214 us; speedup vs baseline: 1.1502x; 1.0082x over previous
//
#include <hip/hip_runtime.h>
#include <math.h>

// Shapes (fixed by the reference)
constexpr int Bn  = 16;
constexpr int Sn  = 512;
constexpr int S2n = 64;
constexpr int Hn  = 128;
constexpr int Ln  = 3;

#define TID ((int)threadIdx.x)

__device__ inline float wave_reduce_sum(float v) {
#pragma unroll
  for (int off = 32; off > 0; off >>= 1) v += __shfl_xor(v, off, 64);
  return v;
}

__device__ inline float block_reduce_sum(float v, float* red) {
  v = wave_reduce_sum(v);
  int w  = TID >> 6;
  int nw = (int)blockDim.x >> 6;
  if ((TID & 63) == 0) red[w] = v;
  __syncthreads();
  float s = 0.f;
  for (int i = 0; i < nw; ++i) s += red[i];
  __syncthreads();
  return s;
}

// Y[M,128] = X[M,K] @ W[:, woff:woff+K]^T (+bias if !accum) (+= if accum)
// v2: 2 cols x 4 rows per thread. Wave's Xs reads are broadcast (whole wave
// shares rbase) -> 4 ds_read_b128 per k-step per wave for 32 FMA/thread.
__global__ __launch_bounds__(256) void gemm_xwT(
    const float* __restrict__ X, const float* __restrict__ W,
    const float* __restrict__ bias, float* __restrict__ Y,
    int M, int K, int wstride, int woff, int accum)
{
  __shared__ float Xs[16 * 256];
  int r0 = blockIdx.x * 16;
  const float* xsrc = X + (size_t)r0 * K;
  int tot4 = (16 * K) >> 2;
  for (int i = TID; i < tot4; i += 256)
    ((float4*)Xs)[i] = ((const float4*)xsrc)[i];
  __syncthreads();

  int col   = TID & 63;          // cols col and col+64
  int rbase = (TID >> 6) * 4;    // 4 rows per thread
  const float* w0 = W + (size_t)col * wstride + woff;
  const float* w1 = W + (size_t)(col + 64) * wstride + woff;
  float acc[4][2] = {};

#pragma unroll 2
  for (int k = 0; k < K; k += 4) {
    float4 wa = *(const float4*)(w0 + k);
    float4 wb = *(const float4*)(w1 + k);
#pragma unroll
    for (int r = 0; r < 4; ++r) {
      float4 x = *(const float4*)&Xs[(rbase + r) * K + k];
      acc[r][0] = fmaf(wa.x, x.x, acc[r][0]);
      acc[r][0] = fmaf(wa.y, x.y, acc[r][0]);
      acc[r][0] = fmaf(wa.z, x.z, acc[r][0]);
      acc[r][0] = fmaf(wa.w, x.w, acc[r][0]);
      acc[r][1] = fmaf(wb.x, x.x, acc[r][1]);
      acc[r][1] = fmaf(wb.y, x.y, acc[r][1]);
      acc[r][1] = fmaf(wb.z, x.z, acc[r][1]);
      acc[r][1] = fmaf(wb.w, x.w, acc[r][1]);
    }
  }
  float bv0 = bias ? bias[col] : 0.f;
  float bv1 = bias ? bias[col + 64] : 0.f;
#pragma unroll
  for (int r = 0; r < 4; ++r) {
    float* y = Y + (size_t)(r0 + rbase + r) * 128 + col;
    if (accum) { y[0] += acc[r][0]; y[64] += acc[r][1]; }
    else       { y[0]  = acc[r][0] + bv0; y[64] = acc[r][1] + bv1; }
  }
}

// a[b,i,c] = sum_j adj[b,i,j] * cat(p,h)[b,j,c]
// Sparse: adjacency is ~5% dense. One wave per output row; ballot-compact
// the adj row, gather only nonzero x-rows (coalesced 1KB float4 loads).
__global__ __launch_bounds__(256) void adj_mm_sparse(
    const float* __restrict__ adj, const float* __restrict__ p,
    const float* __restrict__ h, float* __restrict__ a)
{
  int wid = TID >> 6, lane = TID & 63;
  int b = blockIdx.y;
  int i = blockIdx.x * 4 + wid;          // 4 waves/block, 1 row each

  // lanes 0..31 -> p channels [4*lane,4*lane+4); lanes 32..63 -> h channels
  const float* xbase = (lane < 32)
      ? (p + (size_t)b * Sn * Hn + 4 * lane)
      : (h + (size_t)b * Sn * Hn + 4 * (lane - 32));
  const float* arow = adj + ((size_t)b * Sn + i) * Sn;

  float4 acc = {0.f, 0.f, 0.f, 0.f};
  for (int j0 = 0; j0 < Sn; j0 += 64) {
    float av = arow[j0 + lane];
    unsigned long long mask = __ballot(av != 0.f);
    while (mask) {
      int jj = __ffsll((unsigned long long)mask) - 1;
      mask &= mask - 1;
      float w = __shfl(av, jj, 64);
      float4 x = *(const float4*)(xbase + (size_t)(j0 + jj) * Hn);
      acc.x = fmaf(w, x.x, acc.x);
      acc.y = fmaf(w, x.y, acc.y);
      acc.z = fmaf(w, x.z, acc.z);
      acc.w = fmaf(w, x.w, acc.w);
    }
  }
  int c = (lane < 32) ? 4 * lane : 128 + 4 * (lane - 32);
  *(float4*)(a + ((size_t)b * Sn + i) * (2 * Hn) + c) = acc;
}

// rp <- sigmoid(rp) * h   (elementwise, float4)
__global__ void rh_fuse(const float* __restrict__ h, float* __restrict__ rp, int n4) {
  int i = blockIdx.x * blockDim.x + TID;
  if (i >= n4) return;
  float4 r  = ((const float4*)rp)[i];
  float4 hv = ((const float4*)h)[i];
  r.x = hv.x / (1.f + expf(-r.x));
  r.y = hv.y / (1.f + expf(-r.y));
  r.z = hv.z / (1.f + expf(-r.z));
  r.w = hv.w / (1.f + expf(-r.w));
  ((float4*)rp)[i] = r;
}

// h <- (1-sigmoid(zp))*h + sigmoid(zp)*tanh(hp)
__global__ void gate_combine(float* __restrict__ h, const float* __restrict__ zp,
                             const float* __restrict__ hp, int n4) {
  int i = blockIdx.x * blockDim.x + TID;
  if (i >= n4) return;
  float4 hv = ((const float4*)h)[i];
  float4 z4 = ((const float4*)zp)[i];
  float4 t4 = ((const float4*)hp)[i];
  float z;
  z = 1.f / (1.f + expf(-z4.x)); hv.x = hv.x + z * (tanhf(t4.x) - hv.x);
  z = 1.f / (1.f + expf(-z4.y)); hv.y = hv.y + z * (tanhf(t4.y) - hv.y);
  z = 1.f / (1.f + expf(-z4.z)); hv.z = hv.z + z * (tanhf(t4.z) - hv.z);
  z = 1.f / (1.f + expf(-z4.w)); hv.w = hv.w + z * (tanhf(t4.w) - hv.w);
  ((float4*)h)[i] = hv;
}

// E[b,q,k] = mask ? exp(relu(Wa2 . relu(qp[b,q]+kp[b,k]+ba1) + ba2)) : 0
__global__ __launch_bounds__(256) void scores_exp_v2(
    const float* __restrict__ qp, const float* __restrict__ kp,
    const float* __restrict__ ba1, const float* __restrict__ Wa2,
    const float* __restrict__ ba2, const float* __restrict__ am,
    const float* __restrict__ sm, float* __restrict__ E)
{
  constexpr int KT = 32;
  __shared__ float qs[64][132];
  __shared__ float ks[KT][132];
  __shared__ float w2s[128];
  __shared__ float es[64][33];

  int b = blockIdx.y, kt = blockIdx.x * KT;

  const float* qsrc = qp + (size_t)b * S2n * Hn;
  for (int f = TID; f < 64 * 32; f += 256) {
    int q = f >> 5, g = f & 31;
    float4 v  = ((const float4*)qsrc)[f];
    float4 bb = ((const float4*)ba1)[g];
    v.x += bb.x; v.y += bb.y; v.z += bb.z; v.w += bb.w;
    *(float4*)&qs[q][4 * g] = v;
  }
  const float* ksrc = kp + ((size_t)b * Sn + kt) * Hn;
  for (int f = TID; f < KT * 32; f += 256) {
    int k = f >> 5, g = f & 31;
    *(float4*)&ks[k][4 * g] = ((const float4*)ksrc)[f];
  }
  if (TID < 128) w2s[TID] = Wa2[TID];
  __syncthreads();

  const int q0 = (TID & 15) * 4;
  const int k0 = (TID >> 4) * 2;
  float acc[4][2] = {};

#pragma unroll 4
  for (int h = 0; h < 128; ++h) {
    float w  = w2s[h];
    float kv0 = ks[k0][h], kv1 = ks[k0 + 1][h];
#pragma unroll
    for (int i = 0; i < 4; ++i) {
      float qv = qs[q0 + i][h];
      acc[i][0] = fmaf(fmaxf(qv + kv0, 0.f), w, acc[i][0]);
      acc[i][1] = fmaf(fmaxf(qv + kv1, 0.f), w, acc[i][1]);
    }
  }

  float b2 = ba2[0];
#pragma unroll
  for (int i = 0; i < 4; ++i) {
    float amq = am[b * S2n + q0 + i];
#pragma unroll
    for (int j = 0; j < 2; ++j) {
      float m = amq * sm[b * Sn + kt + k0 + j];
      float s = fmaxf(acc[i][j] + b2, 0.f);
      es[q0 + i][k0 + j] = (m > 0.f) ? expf(s) : 0.f;
    }
  }
  __syncthreads();

  float* Eb = E + ((size_t)b * S2n) * Sn + kt;
  for (int f = TID; f < 64 * KT; f += 256) {
    int q = f >> 5, kin = f & 31;
    Eb[(size_t)q * Sn + kin] = es[q][kin];
  }
}

// sf[b,q,:] = (1/max(sum_k E,2e-15)) * sum_k E[b,q,k]*out[b,k,:]
__global__ __launch_bounds__(128) void attn_sf(
    const float* __restrict__ E, const float* __restrict__ out,
    float* __restrict__ sf)
{
  __shared__ float Es[512];
  __shared__ float red[2];
  int b = blockIdx.y, q = blockIdx.x, t = TID;
  const float* Erow = E + ((size_t)b * S2n + q) * Sn;
  for (int i = t; i < Sn; i += 128) Es[i] = Erow[i];
  __syncthreads();
  float part = Es[t] + Es[t + 128] + Es[t + 256] + Es[t + 384];
  part = wave_reduce_sum(part);
  if ((t & 63) == 0) red[t >> 6] = part;
  __syncthreads();
  float scale = 1.f / fmaxf(red[0] + red[1], 2e-15f);

  const float* ob = out + (size_t)b * Sn * Hn + t;
  float acc = 0.f;
#pragma unroll 8
  for (int k = 0; k < Sn; ++k) acc = fmaf(Es[k], ob[(size_t)k * Hn], acc);
  sf[((size_t)b * S2n + q) * Hn + t] = acc * scale;
}

// sem[b,:] = sum_q sf[b,q,:] / sum_q actions_mask[b,q]
__global__ __launch_bounds__(128) void sem_mean(
    const float* __restrict__ sf, const float* __restrict__ am,
    float* __restrict__ sem)
{
  int b = blockIdx.x, t = TID;
  float acc = 0.f;
  for (int q = 0; q < S2n; ++q) acc += sf[((size_t)b * S2n + q) * Hn + t];
  float num = 0.f;
  for (int i = 0; i < S2n; ++i) num += am[b * S2n + i];
  sem[b * Hn + t] = acc / num;
}

// adv[b,s,l] = sum_h actions[b,s,h] * (weight[l] @ sf[b,s])_h + bias[l]
__global__ __launch_bounds__(128) void adv_kernel(
    const float* __restrict__ actions, const float* __restrict__ sf,
    const float* __restrict__ weight, const float* __restrict__ bias,
    float* __restrict__ adv)
{
  __shared__ float acts[128], sfs[128];
  __shared__ float red[2];
  int b = blockIdx.y, s = blockIdx.x, t = TID;
  size_t row = (size_t)b * S2n + s;
  acts[t] = actions[row * Hn + t];
  sfs[t]  = sf[row * Hn + t];
  __syncthreads();
  for (int l = 0; l < Ln; ++l) {
    const float* wr = weight + ((size_t)l * Hn + t) * Hn;
    float tmp = 0.f;
#pragma unroll 4
    for (int k = 0; k < Hn; k += 4) {
      float4 wv = *(const float4*)(wr + k);
      tmp = fmaf(wv.x, sfs[k],     tmp);
      tmp = fmaf(wv.y, sfs[k + 1], tmp);
      tmp = fmaf(wv.z, sfs[k + 2], tmp);
      tmp = fmaf(wv.w, sfs[k + 3], tmp);
    }
    float pa  = acts[t] * tmp;
    float tot = block_reduce_sum(pa, red);
    if (t == 0) adv[row * Ln + l] = tot + bias[l];
  }
}

// q[b,s,l] = val_b + adv[b,s,l] - mean_{s,l}(adv[b]) ; val_b = Wv.sem[b]+bv
__global__ __launch_bounds__(256) void final_kernel(
    const float* __restrict__ sem, const float* __restrict__ Wv,
    const float* __restrict__ bv, const float* __restrict__ adv,
    float* __restrict__ outq)
{
  __shared__ float red[4];
  int b = blockIdx.x, t = TID;
  float pv  = (t < Hn) ? Wv[t] * sem[b * Hn + t] : 0.f;
  float val = block_reduce_sum(pv, red) + bv[0];
  const float* advb = adv + (size_t)b * S2n * Ln;
  float pa   = (t < S2n * Ln) ? advb[t] : 0.f;
  float mean = block_reduce_sum(pa, red) / (float)(S2n * Ln);
  for (int i = t; i < S2n * Ln; i += 256)
    outq[(size_t)b * S2n * Ln + i] = val + advb[i] - mean;
}

extern "C" void kernel_launch(void* const* d_in, const int* in_sizes, int n_in,
                              void* d_out, int out_size, void* d_ws, size_t ws_size,
                              hipStream_t stream)
{
  const float* states       = (const float*)d_in[0];
  const float* state_mask   = (const float*)d_in[1];
  const float* actions      = (const float*)d_in[2];
  const float* actions_mask = (const float*)d_in[3];
  const float* adj          = (const float*)d_in[4];
  const float* Wn  = (const float*)d_in[5];
  const float* bn  = (const float*)d_in[6];
  const float* Wu  = (const float*)d_in[7];
  const float* bu  = (const float*)d_in[8];
  const float* Wr  = (const float*)d_in[9];
  const float* br  = (const float*)d_in[10];
  const float* Wt  = (const float*)d_in[11];
  const float* bt  = (const float*)d_in[12];
  const float* Wa1 = (const float*)d_in[13];
  const float* ba1 = (const float*)d_in[14];
  const float* Wa2 = (const float*)d_in[15];
  const float* ba2 = (const float*)d_in[16];
  const float* Wv  = (const float*)d_in[17];
  const float* bvp = (const float*)d_in[18];
  const float* weight = (const float*)d_in[19];
  const float* bias   = (const float*)d_in[20];

  // Workspace layout (floats). Total 6 * 2^20 floats = 24 MB.
  float* ws  = (float*)d_ws;
  float* h   = ws;                 // [B,S,H]   1,048,576
  float* p   = ws + (1 << 20);     // [B,S,H]
  float* a   = ws + 2 * (1 << 20); // [B,S,2H]  2,097,152
  float* zp  = ws + 4 * (1 << 20); // [B,S,H]
  float* rp  = ws + 5 * (1 << 20); // [B,S,H]
  float* hp  = a;                  // reuse (a dead after zp/rp gemms)
  float* qp  = a + (1 << 20);      // reuse after GGNN loop (131,072)
  float* kp  = p;                  // reuse after GGNN loop
  float* E   = zp;                 // [B,S2,S] 524,288 (reuse after loop)
  float* sfb = rp;                 // [B,S2,H] 131,072 (reuse after loop)
  float* sem = rp + 135168;        // [B,H]    2,048
  float* adv = rp + 139264;        // [B,S2,L] 3,072

  const int M  = Bn * Sn;          // 8192
  const int n4 = (M * Hn) / 4;     // 262,144

  hipMemcpyAsync(h, states, sizeof(float) * (size_t)M * Hn,
                 hipMemcpyDeviceToDevice, stream);

  for (int step = 0; step < 3; ++step) {
    // p = h @ Wn^T + bn
    gemm_xwT<<<M / 16, 256, 0, stream>>>(h, Wn, bn, p, M, 128, 128, 0, 0);
    // a = adj @ cat(p, h)   (sparse ballot-gather)
    adj_mm_sparse<<<dim3(Sn / 4, Bn), 256, 0, stream>>>(adj, p, h, a);
    // zp = a @ Wu^T + bu ; rp = a @ Wr^T + br
    gemm_xwT<<<M / 16, 256, 0, stream>>>(a, Wu, bu, zp, M, 256, 256, 0, 0);
    gemm_xwT<<<M / 16, 256, 0, stream>>>(a, Wr, br, rp, M, 256, 256, 0, 0);
    // rp <- sigmoid(rp) * h
    rh_fuse<<<n4 / 256, 256, 0, stream>>>(h, rp, n4);
    // hp = p @ WtL^T + bt ; hp += (r*h) @ WtR^T
    gemm_xwT<<<M / 16, 256, 0, stream>>>(p, Wt, bt, hp, M, 128, 256, 0, 0);
    gemm_xwT<<<M / 16, 256, 0, stream>>>(rp, Wt, nullptr, hp, M, 128, 256, 128, 1);
    // h <- (1-z)*h + z*tanh(hp)
    gate_combine<<<n4 / 256, 256, 0, stream>>>(h, zp, hp, n4);
  }

  // qp = actions @ Wa1[:, :H]^T ; kp = out @ Wa1[:, H:]^T   (no bias here)
  gemm_xwT<<<(Bn * S2n) / 16, 256, 0, stream>>>(actions, Wa1, nullptr, qp,
                                                Bn * S2n, 128, 256, 0, 0);
  gemm_xwT<<<M / 16, 256, 0, stream>>>(h, Wa1, nullptr, kp, M, 128, 256, 128, 0);

  scores_exp_v2<<<dim3(Sn / 32, Bn), 256, 0, stream>>>(qp, kp, ba1, Wa2, ba2,
                                                       actions_mask, state_mask, E);
  attn_sf<<<dim3(S2n, Bn), 128, 0, stream>>>(E, h, sfb);
  sem_mean<<<Bn, 128, 0, stream>>>(sfb, actions_mask, sem);
  adv_kernel<<<dim3(S2n, Bn), 128, 0, stream>>>(actions, sfb, weight, bias, adv);
  final_kernel<<<Bn, 256, 0, stream>>>(sem, Wv, bvp, adv, (float*)d_out);
}

// Round 7
// 392.043 us; speedup vs baseline: 1.5614x; 1.3575x over previous
//
#include <hip/hip_runtime.h>
#include <math.h>

// Shapes (fixed by the reference)
constexpr int Bn  = 16;
constexpr int Sn  = 512;
constexpr int S2n = 64;
constexpr int Hn  = 128;
constexpr int Ln  = 3;

#define TID ((int)threadIdx.x)

__device__ inline float wave_reduce_sum(float v) {
#pragma unroll
  for (int off = 32; off > 0; off >>= 1) v += __shfl_xor(v, off, 64);
  return v;
}

__device__ inline float block_reduce_sum(float v, float* red) {
  v = wave_reduce_sum(v);
  int w  = TID >> 6;
  int nw = (int)blockDim.x >> 6;
  if ((TID & 63) == 0) red[w] = v;
  __syncthreads();
  float s = 0.f;
  for (int i = 0; i < nw; ++i) s += red[i];
  __syncthreads();
  return s;
}

// dst[k][n] = src[n*wstride + woff + k], n in [0,128), k in [0,K). 32x32 tiles.
__global__ __launch_bounds__(256) void transpose_w(
    const float* __restrict__ src, float* __restrict__ dst,
    int wstride, int woff)
{
  __shared__ float t[32][33];
  int k0 = blockIdx.x * 32, n0 = blockIdx.y * 32;
  int tx = TID & 31, ty = TID >> 5;          // ty in [0,8)
#pragma unroll
  for (int i = 0; i < 32; i += 8)
    t[ty + i][tx] = src[(size_t)(n0 + ty + i) * wstride + woff + k0 + tx];
  __syncthreads();
#pragma unroll
  for (int i = 0; i < 32; i += 8)
    dst[(size_t)(k0 + ty + i) * 128 + n0 + tx] = t[tx][ty + i];
}

// Y[M,128] (+)= X[M,K] @ WT[K,128] (+bias). WT pre-transposed -> coalesced
// W loads (lanes over cols). 16 rows/block, 4 rows x 2 cols per thread.
__global__ __launch_bounds__(256) void gemm_wt(
    const float* __restrict__ X, const float* __restrict__ WT,
    const float* __restrict__ bias, float* __restrict__ Y,
    int M, int K, int accum)
{
  extern __shared__ float Xs[];              // [16][K]
  int r0 = blockIdx.x * 16;
  const float* xsrc = X + (size_t)r0 * K;
  int tot4 = (16 * K) >> 2;
  for (int i = TID; i < tot4; i += 256)
    ((float4*)Xs)[i] = ((const float4*)xsrc)[i];
  __syncthreads();

  int cg = (TID & 63) * 2;                   // cols cg, cg+1
  int rb = (TID >> 6) * 4;                   // 4 rows
  float acc[4][2] = {};

#pragma unroll 2
  for (int k = 0; k < K; k += 4) {
    const float* wk = WT + (size_t)k * 128 + cg;
    float2 w0 = *(const float2*)(wk);
    float2 w1 = *(const float2*)(wk + 128);
    float2 w2 = *(const float2*)(wk + 256);
    float2 w3 = *(const float2*)(wk + 384);
#pragma unroll
    for (int i = 0; i < 4; ++i) {
      float4 x = *(const float4*)&Xs[(rb + i) * K + k];
      acc[i][0] = fmaf(x.x, w0.x, acc[i][0]);
      acc[i][0] = fmaf(x.y, w1.x, acc[i][0]);
      acc[i][0] = fmaf(x.z, w2.x, acc[i][0]);
      acc[i][0] = fmaf(x.w, w3.x, acc[i][0]);
      acc[i][1] = fmaf(x.x, w0.y, acc[i][1]);
      acc[i][1] = fmaf(x.y, w1.y, acc[i][1]);
      acc[i][1] = fmaf(x.z, w2.y, acc[i][1]);
      acc[i][1] = fmaf(x.w, w3.y, acc[i][1]);
    }
  }

  float2 bv = {0.f, 0.f};
  if (bias) bv = *(const float2*)(bias + cg);
#pragma unroll
  for (int i = 0; i < 4; ++i) {
    float* y = Y + (size_t)(r0 + rb + i) * 128 + cg;
    if (accum) {
      float2 old = *(float2*)y;
      old.x += acc[i][0]; old.y += acc[i][1];
      *(float2*)y = old;
    } else {
      float2 v = {acc[i][0] + bv.x, acc[i][1] + bv.y};
      *(float2*)y = v;
    }
  }
}

// a[b,i,c] = sum_j adj[b,i,j] * cat(p,h)[b,j,c]
// Sparse: adjacency is ~5% dense. One wave per output row; ballot-compact
// the adj row, gather only nonzero x-rows (coalesced 1KB float4 loads).
__global__ __launch_bounds__(256) void adj_mm_sparse(
    const float* __restrict__ adj, const float* __restrict__ p,
    const float* __restrict__ h, float* __restrict__ a)
{
  int wid = TID >> 6, lane = TID & 63;
  int b = blockIdx.y;
  int i = blockIdx.x * 4 + wid;          // 4 waves/block, 1 row each

  const float* xbase = (lane < 32)
      ? (p + (size_t)b * Sn * Hn + 4 * lane)
      : (h + (size_t)b * Sn * Hn + 4 * (lane - 32));
  const float* arow = adj + ((size_t)b * Sn + i) * Sn;

  float4 acc = {0.f, 0.f, 0.f, 0.f};
  for (int j0 = 0; j0 < Sn; j0 += 64) {
    float av = arow[j0 + lane];
    unsigned long long mask = __ballot(av != 0.f);
    while (mask) {
      int jj = __ffsll((unsigned long long)mask) - 1;
      mask &= mask - 1;
      float w = __shfl(av, jj, 64);
      float4 x = *(const float4*)(xbase + (size_t)(j0 + jj) * Hn);
      acc.x = fmaf(w, x.x, acc.x);
      acc.y = fmaf(w, x.y, acc.y);
      acc.z = fmaf(w, x.z, acc.z);
      acc.w = fmaf(w, x.w, acc.w);
    }
  }
  int c = (lane < 32) ? 4 * lane : 128 + 4 * (lane - 32);
  *(float4*)(a + ((size_t)b * Sn + i) * (2 * Hn) + c) = acc;
}

// rp <- sigmoid(rp) * h   (elementwise, float4)
__global__ void rh_fuse(const float* __restrict__ h, float* __restrict__ rp, int n4) {
  int i = blockIdx.x * blockDim.x + TID;
  if (i >= n4) return;
  float4 r  = ((const float4*)rp)[i];
  float4 hv = ((const float4*)h)[i];
  r.x = hv.x / (1.f + expf(-r.x));
  r.y = hv.y / (1.f + expf(-r.y));
  r.z = hv.z / (1.f + expf(-r.z));
  r.w = hv.w / (1.f + expf(-r.w));
  ((float4*)rp)[i] = r;
}

// h <- (1-sigmoid(zp))*h + sigmoid(zp)*tanh(hp)
__global__ void gate_combine(float* __restrict__ h, const float* __restrict__ zp,
                             const float* __restrict__ hp, int n4) {
  int i = blockIdx.x * blockDim.x + TID;
  if (i >= n4) return;
  float4 hv = ((const float4*)h)[i];
  float4 z4 = ((const float4*)zp)[i];
  float4 t4 = ((const float4*)hp)[i];
  float z;
  z = 1.f / (1.f + expf(-z4.x)); hv.x = hv.x + z * (tanhf(t4.x) - hv.x);
  z = 1.f / (1.f + expf(-z4.y)); hv.y = hv.y + z * (tanhf(t4.y) - hv.y);
  z = 1.f / (1.f + expf(-z4.z)); hv.z = hv.z + z * (tanhf(t4.z) - hv.z);
  z = 1.f / (1.f + expf(-z4.w)); hv.w = hv.w + z * (tanhf(t4.w) - hv.w);
  ((float4*)h)[i] = hv;
}

// E[b,q,k] = mask ? exp(relu(Wa2 . relu(qp[b,q]+kp[b,k]+ba1) + ba2)) : 0
__global__ __launch_bounds__(256) void scores_exp_v2(
    const float* __restrict__ qp, const float* __restrict__ kp,
    const float* __restrict__ ba1, const float* __restrict__ Wa2,
    const float* __restrict__ ba2, const float* __restrict__ am,
    const float* __restrict__ sm, float* __restrict__ E)
{
  constexpr int KT = 32;
  __shared__ float qs[64][132];
  __shared__ float ks[KT][132];
  __shared__ float w2s[128];
  __shared__ float es[64][33];

  int b = blockIdx.y, kt = blockIdx.x * KT;

  const float* qsrc = qp + (size_t)b * S2n * Hn;
  for (int f = TID; f < 64 * 32; f += 256) {
    int q = f >> 5, g = f & 31;
    float4 v  = ((const float4*)qsrc)[f];
    float4 bb = ((const float4*)ba1)[g];
    v.x += bb.x; v.y += bb.y; v.z += bb.z; v.w += bb.w;
    *(float4*)&qs[q][4 * g] = v;
  }
  const float* ksrc = kp + ((size_t)b * Sn + kt) * Hn;
  for (int f = TID; f < KT * 32; f += 256) {
    int k = f >> 5, g = f & 31;
    *(float4*)&ks[k][4 * g] = ((const float4*)ksrc)[f];
  }
  if (TID < 128) w2s[TID] = Wa2[TID];
  __syncthreads();

  const int q0 = (TID & 15) * 4;
  const int k0 = (TID >> 4) * 2;
  float acc[4][2] = {};

#pragma unroll 4
  for (int h = 0; h < 128; ++h) {
    float w  = w2s[h];
    float kv0 = ks[k0][h], kv1 = ks[k0 + 1][h];
#pragma unroll
    for (int i = 0; i < 4; ++i) {
      float qv = qs[q0 + i][h];
      acc[i][0] = fmaf(fmaxf(qv + kv0, 0.f), w, acc[i][0]);
      acc[i][1] = fmaf(fmaxf(qv + kv1, 0.f), w, acc[i][1]);
    }
  }

  float b2 = ba2[0];
#pragma unroll
  for (int i = 0; i < 4; ++i) {
    float amq = am[b * S2n + q0 + i];
#pragma unroll
    for (int j = 0; j < 2; ++j) {
      float m = amq * sm[b * Sn + kt + k0 + j];
      float s = fmaxf(acc[i][j] + b2, 0.f);
      es[q0 + i][k0 + j] = (m > 0.f) ? expf(s) : 0.f;
    }
  }
  __syncthreads();

  float* Eb = E + ((size_t)b * S2n) * Sn + kt;
  for (int f = TID; f < 64 * KT; f += 256) {
    int q = f >> 5, kin = f & 31;
    Eb[(size_t)q * Sn + kin] = es[q][kin];
  }
}

// sf[b,q,:] = (1/max(sum_k E,2e-15)) * sum_k E[b,q,k]*out[b,k,:]
__global__ __launch_bounds__(128) void attn_sf(
    const float* __restrict__ E, const float* __restrict__ out,
    float* __restrict__ sf)
{
  __shared__ float Es[512];
  __shared__ float red[2];
  int b = blockIdx.y, q = blockIdx.x, t = TID;
  const float* Erow = E + ((size_t)b * S2n + q) * Sn;
  for (int i = t; i < Sn; i += 128) Es[i] = Erow[i];
  __syncthreads();
  float part = Es[t] + Es[t + 128] + Es[t + 256] + Es[t + 384];
  part = wave_reduce_sum(part);
  if ((t & 63) == 0) red[t >> 6] = part;
  __syncthreads();
  float scale = 1.f / fmaxf(red[0] + red[1], 2e-15f);

  const float* ob = out + (size_t)b * Sn * Hn + t;
  float acc = 0.f;
#pragma unroll 8
  for (int k = 0; k < Sn; ++k) acc = fmaf(Es[k], ob[(size_t)k * Hn], acc);
  sf[((size_t)b * S2n + q) * Hn + t] = acc * scale;
}

// sem[b,:] = sum_q sf[b,q,:] / sum_q actions_mask[b,q]
__global__ __launch_bounds__(128) void sem_mean(
    const float* __restrict__ sf, const float* __restrict__ am,
    float* __restrict__ sem)
{
  int b = blockIdx.x, t = TID;
  float acc = 0.f;
  for (int q = 0; q < S2n; ++q) acc += sf[((size_t)b * S2n + q) * Hn + t];
  float num = 0.f;
  for (int i = 0; i < S2n; ++i) num += am[b * S2n + i];
  sem[b * Hn + t] = acc / num;
}

// adv[b,s,l] = sum_h actions[b,s,h] * (weight[l] @ sf[b,s])_h + bias[l]
__global__ __launch_bounds__(128) void adv_kernel(
    const float* __restrict__ actions, const float* __restrict__ sf,
    const float* __restrict__ weight, const float* __restrict__ bias,
    float* __restrict__ adv)
{
  __shared__ float acts[128], sfs[128];
  __shared__ float red[2];
  int b = blockIdx.y, s = blockIdx.x, t = TID;
  size_t row = (size_t)b * S2n + s;
  acts[t] = actions[row * Hn + t];
  sfs[t]  = sf[row * Hn + t];
  __syncthreads();
  for (int l = 0; l < Ln; ++l) {
    const float* wr = weight + ((size_t)l * Hn + t) * Hn;
    float tmp = 0.f;
#pragma unroll 4
    for (int k = 0; k < Hn; k += 4) {
      float4 wv = *(const float4*)(wr + k);
      tmp = fmaf(wv.x, sfs[k],     tmp);
      tmp = fmaf(wv.y, sfs[k + 1], tmp);
      tmp = fmaf(wv.z, sfs[k + 2], tmp);
      tmp = fmaf(wv.w, sfs[k + 3], tmp);
    }
    float pa  = acts[t] * tmp;
    float tot = block_reduce_sum(pa, red);
    if (t == 0) adv[row * Ln + l] = tot + bias[l];
  }
}

// q[b,s,l] = val_b + adv[b,s,l] - mean_{s,l}(adv[b]) ; val_b = Wv.sem[b]+bv
__global__ __launch_bounds__(256) void final_kernel(
    const float* __restrict__ sem, const float* __restrict__ Wv,
    const float* __restrict__ bv, const float* __restrict__ adv,
    float* __restrict__ outq)
{
  __shared__ float red[4];
  int b = blockIdx.x, t = TID;
  float pv  = (t < Hn) ? Wv[t] * sem[b * Hn + t] : 0.f;
  float val = block_reduce_sum(pv, red) + bv[0];
  const float* advb = adv + (size_t)b * S2n * Ln;
  float pa   = (t < S2n * Ln) ? advb[t] : 0.f;
  float mean = block_reduce_sum(pa, red) / (float)(S2n * Ln);
  for (int i = t; i < S2n * Ln; i += 256)
    outq[(size_t)b * S2n * Ln + i] = val + advb[i] - mean;
}

extern "C" void kernel_launch(void* const* d_in, const int* in_sizes, int n_in,
                              void* d_out, int out_size, void* d_ws, size_t ws_size,
                              hipStream_t stream)
{
  const float* states       = (const float*)d_in[0];
  const float* state_mask   = (const float*)d_in[1];
  const float* actions      = (const float*)d_in[2];
  const float* actions_mask = (const float*)d_in[3];
  const float* adj          = (const float*)d_in[4];
  const float* Wn  = (const float*)d_in[5];
  const float* bn  = (const float*)d_in[6];
  const float* Wu  = (const float*)d_in[7];
  const float* bu  = (const float*)d_in[8];
  const float* Wr  = (const float*)d_in[9];
  const float* br  = (const float*)d_in[10];
  const float* Wt  = (const float*)d_in[11];
  const float* bt  = (const float*)d_in[12];
  const float* Wa1 = (const float*)d_in[13];
  const float* ba1 = (const float*)d_in[14];
  const float* Wa2 = (const float*)d_in[15];
  const float* ba2 = (const float*)d_in[16];
  const float* Wv  = (const float*)d_in[17];
  const float* bvp = (const float*)d_in[18];
  const float* weight = (const float*)d_in[19];
  const float* bias   = (const float*)d_in[20];

  // Workspace layout (floats). ws_size = 256 MB (fill counter showed 256 MiB).
  float* ws  = (float*)d_ws;
  float* h   = ws;                 // [B,S,H]   1,048,576
  float* p   = ws + (1 << 20);     // [B,S,H]
  float* a   = ws + 2 * (1 << 20); // [B,S,2H]  2,097,152
  float* zp  = ws + 4 * (1 << 20); // [B,S,H]
  float* rp  = ws + 5 * (1 << 20); // [B,S,H]
  float* hp  = a;                  // reuse (a dead after zp/rp gemms)
  float* qp  = a + (1 << 20);      // reuse after GGNN loop (131,072)
  float* kp  = p;                  // reuse after GGNN loop
  float* E   = zp;                 // [B,S2,S] 524,288 (reuse after loop)
  float* sfb = rp;                 // [B,S2,H] 131,072 (reuse after loop)
  float* sem = rp + 135168;        // [B,H]    2,048
  float* adv = rp + 139264;        // [B,S2,L] 3,072
  // Transposed weights (beyond the 6M-float working set):
  float* WnT   = ws + 6 * (1 << 20);   // [128][128] 16,384
  float* WuT   = WnT + 16384;          // [256][128] 32,768
  float* WrT   = WuT + 32768;          // [256][128] 32,768
  float* WtTL  = WrT + 32768;          // [128][128]
  float* WtTR  = WtTL + 16384;         // [128][128]
  float* Wa1TL = WtTR + 16384;         // [128][128]
  float* Wa1TR = Wa1TL + 16384;        // [128][128]

  const int M  = Bn * Sn;          // 8192
  const int n4 = (M * Hn) / 4;     // 262,144

  // One-time weight transposes (coalesced gemm W-loads afterwards)
  transpose_w<<<dim3(4, 4), 256, 0, stream>>>(Wn,  WnT,   128, 0);
  transpose_w<<<dim3(8, 4), 256, 0, stream>>>(Wu,  WuT,   256, 0);
  transpose_w<<<dim3(8, 4), 256, 0, stream>>>(Wr,  WrT,   256, 0);
  transpose_w<<<dim3(4, 4), 256, 0, stream>>>(Wt,  WtTL,  256, 0);
  transpose_w<<<dim3(4, 4), 256, 0, stream>>>(Wt,  WtTR,  256, 128);
  transpose_w<<<dim3(4, 4), 256, 0, stream>>>(Wa1, Wa1TL, 256, 0);
  transpose_w<<<dim3(4, 4), 256, 0, stream>>>(Wa1, Wa1TR, 256, 128);

  hipMemcpyAsync(h, states, sizeof(float) * (size_t)M * Hn,
                 hipMemcpyDeviceToDevice, stream);

  const int lds128 = 16 * 128 * 4;   // Xs bytes for K=128
  const int lds256 = 16 * 256 * 4;   // Xs bytes for K=256

  for (int step = 0; step < 3; ++step) {
    // p = h @ Wn^T + bn
    gemm_wt<<<M / 16, 256, lds128, stream>>>(h, WnT, bn, p, M, 128, 0);
    // a = adj @ cat(p, h)   (sparse ballot-gather)
    adj_mm_sparse<<<dim3(Sn / 4, Bn), 256, 0, stream>>>(adj, p, h, a);
    // zp = a @ Wu^T + bu ; rp = a @ Wr^T + br
    gemm_wt<<<M / 16, 256, lds256, stream>>>(a, WuT, bu, zp, M, 256, 0);
    gemm_wt<<<M / 16, 256, lds256, stream>>>(a, WrT, br, rp, M, 256, 0);
    // rp <- sigmoid(rp) * h
    rh_fuse<<<n4 / 256, 256, 0, stream>>>(h, rp, n4);
    // hp = p @ WtL^T + bt ; hp += (r*h) @ WtR^T
    gemm_wt<<<M / 16, 256, lds128, stream>>>(p,  WtTL, bt, hp, M, 128, 0);
    gemm_wt<<<M / 16, 256, lds128, stream>>>(rp, WtTR, nullptr, hp, M, 128, 1);
    // h <- (1-z)*h + z*tanh(hp)
    gate_combine<<<n4 / 256, 256, 0, stream>>>(h, zp, hp, n4);
  }

  // qp = actions @ Wa1[:, :H]^T ; kp = out @ Wa1[:, H:]^T   (no bias here)
  gemm_wt<<<(Bn * S2n) / 16, 256, lds128, stream>>>(actions, Wa1TL, nullptr, qp,
                                                    Bn * S2n, 128, 0);
  gemm_wt<<<M / 16, 256, lds128, stream>>>(h, Wa1TR, nullptr, kp, M, 128, 0);

  scores_exp_v2<<<dim3(Sn / 32, Bn), 256, 0, stream>>>(qp, kp, ba1, Wa2, ba2,
                                                       actions_mask, state_mask, E);
  attn_sf<<<dim3(S2n, Bn), 128, 0, stream>>>(E, h, sfb);
  sem_mean<<<Bn, 128, 0, stream>>>(sfb, actions_mask, sem);
  adv_kernel<<<dim3(S2n, Bn), 128, 0, stream>>>(actions, sfb, weight, bias, adv);
  final_kernel<<<Bn, 256, 0, stream>>>(sem, Wv, bvp, adv, (float*)d_out);
}

// Round 8
// 343.153 us; speedup vs baseline: 1.7838x; 1.1425x over previous
//
#include <hip/hip_runtime.h>
#include <math.h>

// Shapes (fixed by the reference)
constexpr int Bn  = 16;
constexpr int Sn  = 512;
constexpr int S2n = 64;
constexpr int Hn  = 128;
constexpr int Ln  = 3;

#define TID ((int)threadIdx.x)

__device__ inline float wave_reduce_sum(float v) {
#pragma unroll
  for (int off = 32; off > 0; off >>= 1) v += __shfl_xor(v, off, 64);
  return v;
}

__device__ inline float block_reduce_sum(float v, float* red) {
  v = wave_reduce_sum(v);
  int w  = TID >> 6;
  int nw = (int)blockDim.x >> 6;
  if ((TID & 63) == 0) red[w] = v;
  __syncthreads();
  float s = 0.f;
  for (int i = 0; i < nw; ++i) s += red[i];
  __syncthreads();
  return s;
}

__device__ inline float sigm(float x) { return 1.f / (1.f + expf(-x)); }

// All weight transposes in ONE dispatch. dst[k][n] = src[n*stride + k].
// z: 0=Wn(K=128), 1=Wu, 2=Wr, 3=Wt, 4=Wa1 (K=256, full transpose -> the
// concatenated [256][128] layout gives TL rows 0..127, TR rows 128..255).
__global__ __launch_bounds__(256) void transpose_all(
    const float* __restrict__ Wn, const float* __restrict__ Wu,
    const float* __restrict__ Wr, const float* __restrict__ Wt,
    const float* __restrict__ Wa1,
    float* __restrict__ WnT, float* __restrict__ WuT,
    float* __restrict__ WrT, float* __restrict__ WtT,
    float* __restrict__ Wa1T)
{
  const float* src; float* dst; int K, stride;
  switch (blockIdx.z) {
    case 0:  src = Wn;  dst = WnT;  K = 128; stride = 128; break;
    case 1:  src = Wu;  dst = WuT;  K = 256; stride = 256; break;
    case 2:  src = Wr;  dst = WrT;  K = 256; stride = 256; break;
    case 3:  src = Wt;  dst = WtT;  K = 256; stride = 256; break;
    default: src = Wa1; dst = Wa1T; K = 256; stride = 256; break;
  }
  int k0 = blockIdx.x * 32;
  if (k0 >= K) return;
  int n0 = blockIdx.y * 32;
  __shared__ float t[32][33];
  int tx = TID & 31, ty = TID >> 5;
#pragma unroll
  for (int i = 0; i < 32; i += 8)
    t[ty + i][tx] = src[(size_t)(n0 + ty + i) * stride + k0 + tx];
  __syncthreads();
#pragma unroll
  for (int i = 0; i < 32; i += 8)
    dst[(size_t)(k0 + ty + i) * 128 + n0 + tx] = t[tx][ty + i];
}

// Y[M,128] (+)= X[M,K] @ WT[K,128] (+bias). WT pre-transposed -> coalesced
// W loads. 16 rows/block, 4 rows x 2 cols per thread.
__global__ __launch_bounds__(256) void gemm_wt(
    const float* __restrict__ X, const float* __restrict__ WT,
    const float* __restrict__ bias, float* __restrict__ Y,
    int M, int K, int accum)
{
  extern __shared__ float Xs[];              // [16][K]
  int r0 = blockIdx.x * 16;
  const float* xsrc = X + (size_t)r0 * K;
  int tot4 = (16 * K) >> 2;
  for (int i = TID; i < tot4; i += 256)
    ((float4*)Xs)[i] = ((const float4*)xsrc)[i];
  __syncthreads();

  int cg = (TID & 63) * 2;
  int rb = (TID >> 6) * 4;
  float acc[4][2] = {};

#pragma unroll 2
  for (int k = 0; k < K; k += 4) {
    const float* wk = WT + (size_t)k * 128 + cg;
    float2 w0 = *(const float2*)(wk);
    float2 w1 = *(const float2*)(wk + 128);
    float2 w2 = *(const float2*)(wk + 256);
    float2 w3 = *(const float2*)(wk + 384);
#pragma unroll
    for (int i = 0; i < 4; ++i) {
      float4 x = *(const float4*)&Xs[(rb + i) * K + k];
      acc[i][0] = fmaf(x.x, w0.x, acc[i][0]);
      acc[i][0] = fmaf(x.y, w1.x, acc[i][0]);
      acc[i][0] = fmaf(x.z, w2.x, acc[i][0]);
      acc[i][0] = fmaf(x.w, w3.x, acc[i][0]);
      acc[i][1] = fmaf(x.x, w0.y, acc[i][1]);
      acc[i][1] = fmaf(x.y, w1.y, acc[i][1]);
      acc[i][1] = fmaf(x.z, w2.y, acc[i][1]);
      acc[i][1] = fmaf(x.w, w3.y, acc[i][1]);
    }
  }

  float2 bv = {0.f, 0.f};
  if (bias) bv = *(const float2*)(bias + cg);
#pragma unroll
  for (int i = 0; i < 4; ++i) {
    float* y = Y + (size_t)(r0 + rb + i) * 128 + cg;
    if (accum) {
      float2 old = *(float2*)y;
      old.x += acc[i][0]; old.y += acc[i][1];
      *(float2*)y = old;
    } else {
      float2 v = {acc[i][0] + bv.x, acc[i][1] + bv.y};
      *(float2*)y = v;
    }
  }
}

// Fused gate gemms: z = sigmoid(a@Wu^T+bu), rh = sigmoid(a@Wr^T+br)*h.
// One Xs staging serves both weight matrices (64 FMA per k-quad/thread).
__global__ __launch_bounds__(256) void gemm_zr(
    const float* __restrict__ A, const float* __restrict__ WuT,
    const float* __restrict__ WrT, const float* __restrict__ bu,
    const float* __restrict__ br, const float* __restrict__ h,
    float* __restrict__ z, float* __restrict__ rh)
{
  __shared__ float Xs[16 * 256];
  int r0 = blockIdx.x * 16;
  const float* xsrc = A + (size_t)r0 * 256;
  for (int i = TID; i < 1024; i += 256)
    ((float4*)Xs)[i] = ((const float4*)xsrc)[i];
  __syncthreads();

  int cg = (TID & 63) * 2;
  int rb = (TID >> 6) * 4;
  float aU[4][2] = {}, aR[4][2] = {};

#pragma unroll 2
  for (int k = 0; k < 256; k += 4) {
    const float* wu = WuT + (size_t)k * 128 + cg;
    const float* wr = WrT + (size_t)k * 128 + cg;
    float2 u0 = *(const float2*)(wu);
    float2 u1 = *(const float2*)(wu + 128);
    float2 u2 = *(const float2*)(wu + 256);
    float2 u3 = *(const float2*)(wu + 384);
    float2 q0 = *(const float2*)(wr);
    float2 q1 = *(const float2*)(wr + 128);
    float2 q2 = *(const float2*)(wr + 256);
    float2 q3 = *(const float2*)(wr + 384);
#pragma unroll
    for (int i = 0; i < 4; ++i) {
      float4 x = *(const float4*)&Xs[(rb + i) * 256 + k];
      aU[i][0] = fmaf(x.x, u0.x, aU[i][0]);
      aU[i][0] = fmaf(x.y, u1.x, aU[i][0]);
      aU[i][0] = fmaf(x.z, u2.x, aU[i][0]);
      aU[i][0] = fmaf(x.w, u3.x, aU[i][0]);
      aU[i][1] = fmaf(x.x, u0.y, aU[i][1]);
      aU[i][1] = fmaf(x.y, u1.y, aU[i][1]);
      aU[i][1] = fmaf(x.z, u2.y, aU[i][1]);
      aU[i][1] = fmaf(x.w, u3.y, aU[i][1]);
      aR[i][0] = fmaf(x.x, q0.x, aR[i][0]);
      aR[i][0] = fmaf(x.y, q1.x, aR[i][0]);
      aR[i][0] = fmaf(x.z, q2.x, aR[i][0]);
      aR[i][0] = fmaf(x.w, q3.x, aR[i][0]);
      aR[i][1] = fmaf(x.x, q0.y, aR[i][1]);
      aR[i][1] = fmaf(x.y, q1.y, aR[i][1]);
      aR[i][1] = fmaf(x.z, q2.y, aR[i][1]);
      aR[i][1] = fmaf(x.w, q3.y, aR[i][1]);
    }
  }

  float2 buv = *(const float2*)(bu + cg);
  float2 brv = *(const float2*)(br + cg);
#pragma unroll
  for (int i = 0; i < 4; ++i) {
    size_t row = r0 + rb + i;
    float2 hv = *(const float2*)(h + row * 128 + cg);
    float2 zv = {sigm(aU[i][0] + buv.x), sigm(aU[i][1] + buv.y)};
    float2 rv = {sigm(aR[i][0] + brv.x) * hv.x,
                 sigm(aR[i][1] + brv.y) * hv.y};
    *(float2*)(z  + row * 128 + cg) = zv;
    *(float2*)(rh + row * 128 + cg) = rv;
  }
}

// Fused candidate gemm + gate combine:
// h <- h + z*(tanh([p|rh]@WtT + bt) - h). Stages [p|rh] as one 16x256 tile.
__global__ __launch_bounds__(256) void gemm_hp(
    const float* __restrict__ p, const float* __restrict__ rh,
    const float* __restrict__ WtT, const float* __restrict__ bt,
    const float* __restrict__ z, float* __restrict__ h)
{
  __shared__ float Xs[16 * 256];
  int r0 = blockIdx.x * 16;
  const float* psrc = p  + (size_t)r0 * 128;
  const float* rsrc = rh + (size_t)r0 * 128;
  for (int i = TID; i < 512; i += 256) {
    int row = i >> 5, g = i & 31;
    *(float4*)&Xs[row * 256 + 4 * g] =
        ((const float4*)(psrc + (size_t)row * 128))[g];
    *(float4*)&Xs[row * 256 + 128 + 4 * g] =
        ((const float4*)(rsrc + (size_t)row * 128))[g];
  }
  __syncthreads();

  int cg = (TID & 63) * 2;
  int rb = (TID >> 6) * 4;
  float acc[4][2] = {};

#pragma unroll 2
  for (int k = 0; k < 256; k += 4) {
    const float* wk = WtT + (size_t)k * 128 + cg;
    float2 w0 = *(const float2*)(wk);
    float2 w1 = *(const float2*)(wk + 128);
    float2 w2 = *(const float2*)(wk + 256);
    float2 w3 = *(const float2*)(wk + 384);
#pragma unroll
    for (int i = 0; i < 4; ++i) {
      float4 x = *(const float4*)&Xs[(rb + i) * 256 + k];
      acc[i][0] = fmaf(x.x, w0.x, acc[i][0]);
      acc[i][0] = fmaf(x.y, w1.x, acc[i][0]);
      acc[i][0] = fmaf(x.z, w2.x, acc[i][0]);
      acc[i][0] = fmaf(x.w, w3.x, acc[i][0]);
      acc[i][1] = fmaf(x.x, w0.y, acc[i][1]);
      acc[i][1] = fmaf(x.y, w1.y, acc[i][1]);
      acc[i][1] = fmaf(x.z, w2.y, acc[i][1]);
      acc[i][1] = fmaf(x.w, w3.y, acc[i][1]);
    }
  }

  float2 btv = *(const float2*)(bt + cg);
#pragma unroll
  for (int i = 0; i < 4; ++i) {
    size_t row = r0 + rb + i;
    float*       hrow = h + row * 128 + cg;
    float2 hv = *(float2*)hrow;
    float2 zv = *(const float2*)(z + row * 128 + cg);
    float t0 = tanhf(acc[i][0] + btv.x);
    float t1 = tanhf(acc[i][1] + btv.y);
    hv.x += zv.x * (t0 - hv.x);
    hv.y += zv.y * (t1 - hv.y);
    *(float2*)hrow = hv;
  }
}

// a[b,i,c] = sum_j adj[b,i,j] * cat(p,h)[b,j,c]  (ballot-compacted sparse)
__global__ __launch_bounds__(256) void adj_mm_sparse(
    const float* __restrict__ adj, const float* __restrict__ p,
    const float* __restrict__ h, float* __restrict__ a)
{
  int wid = TID >> 6, lane = TID & 63;
  int b = blockIdx.y;
  int i = blockIdx.x * 4 + wid;

  const float* xbase = (lane < 32)
      ? (p + (size_t)b * Sn * Hn + 4 * lane)
      : (h + (size_t)b * Sn * Hn + 4 * (lane - 32));
  const float* arow = adj + ((size_t)b * Sn + i) * Sn;

  float4 acc = {0.f, 0.f, 0.f, 0.f};
  for (int j0 = 0; j0 < Sn; j0 += 64) {
    float av = arow[j0 + lane];
    unsigned long long mask = __ballot(av != 0.f);
    while (mask) {
      int jj = __ffsll((unsigned long long)mask) - 1;
      mask &= mask - 1;
      float w = __shfl(av, jj, 64);
      float4 x = *(const float4*)(xbase + (size_t)(j0 + jj) * Hn);
      acc.x = fmaf(w, x.x, acc.x);
      acc.y = fmaf(w, x.y, acc.y);
      acc.z = fmaf(w, x.z, acc.z);
      acc.w = fmaf(w, x.w, acc.w);
    }
  }
  int c = (lane < 32) ? 4 * lane : 128 + 4 * (lane - 32);
  *(float4*)(a + ((size_t)b * Sn + i) * (2 * Hn) + c) = acc;
}

// E[b,q,k] = mask ? exp(relu(Wa2 . relu(qp[b,q]+kp[b,k]+ba1) + ba2)) : 0
__global__ __launch_bounds__(256) void scores_exp_v2(
    const float* __restrict__ qp, const float* __restrict__ kp,
    const float* __restrict__ ba1, const float* __restrict__ Wa2,
    const float* __restrict__ ba2, const float* __restrict__ am,
    const float* __restrict__ sm, float* __restrict__ E)
{
  constexpr int KT = 32;
  __shared__ float qs[64][132];
  __shared__ float ks[KT][132];
  __shared__ float w2s[128];
  __shared__ float es[64][33];

  int b = blockIdx.y, kt = blockIdx.x * KT;

  const float* qsrc = qp + (size_t)b * S2n * Hn;
  for (int f = TID; f < 64 * 32; f += 256) {
    int q = f >> 5, g = f & 31;
    float4 v  = ((const float4*)qsrc)[f];
    float4 bb = ((const float4*)ba1)[g];
    v.x += bb.x; v.y += bb.y; v.z += bb.z; v.w += bb.w;
    *(float4*)&qs[q][4 * g] = v;
  }
  const float* ksrc = kp + ((size_t)b * Sn + kt) * Hn;
  for (int f = TID; f < KT * 32; f += 256) {
    int k = f >> 5, g = f & 31;
    *(float4*)&ks[k][4 * g] = ((const float4*)ksrc)[f];
  }
  if (TID < 128) w2s[TID] = Wa2[TID];
  __syncthreads();

  const int q0 = (TID & 15) * 4;
  const int k0 = (TID >> 4) * 2;
  float acc[4][2] = {};

#pragma unroll 4
  for (int h = 0; h < 128; ++h) {
    float w  = w2s[h];
    float kv0 = ks[k0][h], kv1 = ks[k0 + 1][h];
#pragma unroll
    for (int i = 0; i < 4; ++i) {
      float qv = qs[q0 + i][h];
      acc[i][0] = fmaf(fmaxf(qv + kv0, 0.f), w, acc[i][0]);
      acc[i][1] = fmaf(fmaxf(qv + kv1, 0.f), w, acc[i][1]);
    }
  }

  float b2 = ba2[0];
#pragma unroll
  for (int i = 0; i < 4; ++i) {
    float amq = am[b * S2n + q0 + i];
#pragma unroll
    for (int j = 0; j < 2; ++j) {
      float m = amq * sm[b * Sn + kt + k0 + j];
      float s = fmaxf(acc[i][j] + b2, 0.f);
      es[q0 + i][k0 + j] = (m > 0.f) ? expf(s) : 0.f;
    }
  }
  __syncthreads();

  float* Eb = E + ((size_t)b * S2n) * Sn + kt;
  for (int f = TID; f < 64 * KT; f += 256) {
    int q = f >> 5, kin = f & 31;
    Eb[(size_t)q * Sn + kin] = es[q][kin];
  }
}

// sf[b,q,:] = (1/max(sum_k E,2e-15)) * sum_k E[b,q,k]*out[b,k,:]
__global__ __launch_bounds__(128) void attn_sf(
    const float* __restrict__ E, const float* __restrict__ out,
    float* __restrict__ sf)
{
  __shared__ float Es[512];
  __shared__ float red[2];
  int b = blockIdx.y, q = blockIdx.x, t = TID;
  const float* Erow = E + ((size_t)b * S2n + q) * Sn;
  for (int i = t; i < Sn; i += 128) Es[i] = Erow[i];
  __syncthreads();
  float part = Es[t] + Es[t + 128] + Es[t + 256] + Es[t + 384];
  part = wave_reduce_sum(part);
  if ((t & 63) == 0) red[t >> 6] = part;
  __syncthreads();
  float scale = 1.f / fmaxf(red[0] + red[1], 2e-15f);

  const float* ob = out + (size_t)b * Sn * Hn + t;
  float acc = 0.f;
#pragma unroll 8
  for (int k = 0; k < Sn; ++k) acc = fmaf(Es[k], ob[(size_t)k * Hn], acc);
  sf[((size_t)b * S2n + q) * Hn + t] = acc * scale;
}

// sem[b,:] = sum_q sf[b,q,:] / sum_q actions_mask[b,q]
__global__ __launch_bounds__(128) void sem_mean(
    const float* __restrict__ sf, const float* __restrict__ am,
    float* __restrict__ sem)
{
  int b = blockIdx.x, t = TID;
  float acc = 0.f;
  for (int q = 0; q < S2n; ++q) acc += sf[((size_t)b * S2n + q) * Hn + t];
  float num = 0.f;
  for (int i = 0; i < S2n; ++i) num += am[b * S2n + i];
  sem[b * Hn + t] = acc / num;
}

// adv[b,s,l] = sum_h actions[b,s,h] * (weight[l] @ sf[b,s])_h + bias[l]
__global__ __launch_bounds__(128) void adv_kernel(
    const float* __restrict__ actions, const float* __restrict__ sf,
    const float* __restrict__ weight, const float* __restrict__ bias,
    float* __restrict__ adv)
{
  __shared__ float acts[128], sfs[128];
  __shared__ float red[2];
  int b = blockIdx.y, s = blockIdx.x, t = TID;
  size_t row = (size_t)b * S2n + s;
  acts[t] = actions[row * Hn + t];
  sfs[t]  = sf[row * Hn + t];
  __syncthreads();
  for (int l = 0; l < Ln; ++l) {
    const float* wr = weight + ((size_t)l * Hn + t) * Hn;
    float tmp = 0.f;
#pragma unroll 4
    for (int k = 0; k < Hn; k += 4) {
      float4 wv = *(const float4*)(wr + k);
      tmp = fmaf(wv.x, sfs[k],     tmp);
      tmp = fmaf(wv.y, sfs[k + 1], tmp);
      tmp = fmaf(wv.z, sfs[k + 2], tmp);
      tmp = fmaf(wv.w, sfs[k + 3], tmp);
    }
    float pa  = acts[t] * tmp;
    float tot = block_reduce_sum(pa, red);
    if (t == 0) adv[row * Ln + l] = tot + bias[l];
  }
}

// q[b,s,l] = val_b + adv[b,s,l] - mean_{s,l}(adv[b]) ; val_b = Wv.sem[b]+bv
__global__ __launch_bounds__(256) void final_kernel(
    const float* __restrict__ sem, const float* __restrict__ Wv,
    const float* __restrict__ bv, const float* __restrict__ adv,
    float* __restrict__ outq)
{
  __shared__ float red[4];
  int b = blockIdx.x, t = TID;
  float pv  = (t < Hn) ? Wv[t] * sem[b * Hn + t] : 0.f;
  float val = block_reduce_sum(pv, red) + bv[0];
  const float* advb = adv + (size_t)b * S2n * Ln;
  float pa   = (t < S2n * Ln) ? advb[t] : 0.f;
  float mean = block_reduce_sum(pa, red) / (float)(S2n * Ln);
  for (int i = t; i < S2n * Ln; i += 256)
    outq[(size_t)b * S2n * Ln + i] = val + advb[i] - mean;
}

extern "C" void kernel_launch(void* const* d_in, const int* in_sizes, int n_in,
                              void* d_out, int out_size, void* d_ws, size_t ws_size,
                              hipStream_t stream)
{
  const float* states       = (const float*)d_in[0];
  const float* state_mask   = (const float*)d_in[1];
  const float* actions      = (const float*)d_in[2];
  const float* actions_mask = (const float*)d_in[3];
  const float* adj          = (const float*)d_in[4];
  const float* Wn  = (const float*)d_in[5];
  const float* bn  = (const float*)d_in[6];
  const float* Wu  = (const float*)d_in[7];
  const float* bu  = (const float*)d_in[8];
  const float* Wr  = (const float*)d_in[9];
  const float* br  = (const float*)d_in[10];
  const float* Wt  = (const float*)d_in[11];
  const float* bt  = (const float*)d_in[12];
  const float* Wa1 = (const float*)d_in[13];
  const float* ba1 = (const float*)d_in[14];
  const float* Wa2 = (const float*)d_in[15];
  const float* ba2 = (const float*)d_in[16];
  const float* Wv  = (const float*)d_in[17];
  const float* bvp = (const float*)d_in[18];
  const float* weight = (const float*)d_in[19];
  const float* bias   = (const float*)d_in[20];

  // Workspace layout (floats). ws_size = 256 MB.
  float* ws  = (float*)d_ws;
  float* h   = ws;                 // [B,S,H]   1,048,576
  float* p   = ws + (1 << 20);     // [B,S,H]
  float* a   = ws + 2 * (1 << 20); // [B,S,2H]  2,097,152
  float* zp  = ws + 4 * (1 << 20); // [B,S,H]  (stores sigmoid(z))
  float* rp  = ws + 5 * (1 << 20); // [B,S,H]  (stores sigmoid(r)*h)
  float* qp  = a + (1 << 20);      // reuse after GGNN loop
  float* kp  = p;                  // reuse after GGNN loop
  float* E   = zp;                 // [B,S2,S] reuse after loop
  float* sfb = rp;                 // [B,S2,H] reuse after loop
  float* sem = rp + 135168;        // [B,H]
  float* adv = rp + 139264;        // [B,S2,L]
  // Transposed weights:
  float* WnT  = ws + 6 * (1 << 20);  // [128][128]
  float* WuT  = WnT + 16384;         // [256][128]
  float* WrT  = WuT + 32768;         // [256][128]
  float* WtT  = WrT + 32768;         // [256][128]
  float* Wa1T = WtT + 32768;         // [256][128] (rows 0..127=TL, 128..255=TR)

  const int M = Bn * Sn;             // 8192

  transpose_all<<<dim3(8, 4, 5), 256, 0, stream>>>(
      Wn, Wu, Wr, Wt, Wa1, WnT, WuT, WrT, WtT, Wa1T);

  hipMemcpyAsync(h, states, sizeof(float) * (size_t)M * Hn,
                 hipMemcpyDeviceToDevice, stream);

  const int lds128 = 16 * 128 * 4;

  for (int step = 0; step < 3; ++step) {
    // p = h @ Wn^T + bn
    gemm_wt<<<M / 16, 256, lds128, stream>>>(h, WnT, bn, p, M, 128, 0);
    // a = adj @ cat(p, h)
    adj_mm_sparse<<<dim3(Sn / 4, Bn), 256, 0, stream>>>(adj, p, h, a);
    // z = sigmoid(a@Wu^T+bu); rh = sigmoid(a@Wr^T+br)*h
    gemm_zr<<<M / 16, 256, 0, stream>>>(a, WuT, WrT, bu, br, h, zp, rp);
    // h <- h + z*(tanh([p|rh]@WtT + bt) - h)
    gemm_hp<<<M / 16, 256, 0, stream>>>(p, rp, WtT, bt, zp, h);
  }

  // qp = actions @ Wa1TL ; kp = h @ Wa1TR
  gemm_wt<<<(Bn * S2n) / 16, 256, lds128, stream>>>(actions, Wa1T, nullptr, qp,
                                                    Bn * S2n, 128, 0);
  gemm_wt<<<M / 16, 256, lds128, stream>>>(h, Wa1T + 128 * 128, nullptr, kp,
                                           M, 128, 0);

  scores_exp_v2<<<dim3(Sn / 32, Bn), 256, 0, stream>>>(qp, kp, ba1, Wa2, ba2,
                                                       actions_mask, state_mask, E);
  attn_sf<<<dim3(S2n, Bn), 128, 0, stream>>>(E, h, sfb);
  sem_mean<<<Bn, 128, 0, stream>>>(sfb, actions_mask, sem);
  adv_kernel<<<dim3(S2n, Bn), 128, 0, stream>>>(actions, sfb, weight, bias, adv);
  final_kernel<<<Bn, 256, 0, stream>>>(sem, Wv, bvp, adv, (float*)d_out);
}